// Round 1
// baseline (532.125 us; speedup 1.0000x reference)
//
#include <hip/hip_runtime.h>
#include <hip/hip_bf16.h>
#include <math.h>

#define B 64
#define N 512
#define C 1024
#define K_NEIGH 32

// ---------------------------------------------------------------------------
// Kernel 1: batched symmetric GEMM  S[b] = x[b] * x[b]^T   (fp32, vector ALU)
// 64x64 output tile per block, 256 threads, 4x4 micro-tile per thread.
// Only upper-triangular tile pairs computed (tj >= ti); mirror on store.
// ---------------------------------------------------------------------------
#define TK 32
#define LDA 68  // 64 + 4 pad: keeps float4 alignment (68*4 % 16 == 0), breaks bank conflicts

__global__ __launch_bounds__(256) void gemm_syrk(const float* __restrict__ x,
                                                 float* __restrict__ S) {
    __shared__ float As[TK][LDA];
    __shared__ float Bs[TK][LDA];

    const int b = blockIdx.x;
    int p = blockIdx.y;           // 0..35 -> (ti, tj) with tj >= ti over 8x8 tiles
    int ti = 0;
    while (p >= (8 - ti)) { p -= (8 - ti); ti++; }
    const int tj = ti + p;

    const int tid = threadIdx.x;
    const int tx = tid & 15;       // 0..15 -> output cols tx*4..tx*4+3
    const int ty = tid >> 4;       // 0..15 -> output rows ty*4..ty*4+3

    const int row0A = ti * 64;
    const int row0B = tj * 64;
    const float* xb = x + (size_t)b * N * C;

    float acc[4][4];
#pragma unroll
    for (int i = 0; i < 4; i++)
#pragma unroll
        for (int j = 0; j < 4; j++) acc[i][j] = 0.f;

    for (int kt = 0; kt < C; kt += TK) {
        // stage A and B tiles (64 rows x 32 k), transposed to k-major in LDS
#pragma unroll
        for (int it = 0; it < 2; it++) {
            const int pos = tid + it * 256;     // 0..511 float4 slots
            const int r   = pos >> 3;           // 0..63
            const int c4  = pos & 7;            // 0..7
            float4 va = *(const float4*)(xb + (size_t)(row0A + r) * C + kt + c4 * 4);
            As[c4 * 4 + 0][r] = va.x;
            As[c4 * 4 + 1][r] = va.y;
            As[c4 * 4 + 2][r] = va.z;
            As[c4 * 4 + 3][r] = va.w;
            float4 vb = *(const float4*)(xb + (size_t)(row0B + r) * C + kt + c4 * 4);
            Bs[c4 * 4 + 0][r] = vb.x;
            Bs[c4 * 4 + 1][r] = vb.y;
            Bs[c4 * 4 + 2][r] = vb.z;
            Bs[c4 * 4 + 3][r] = vb.w;
        }
        __syncthreads();

#pragma unroll
        for (int k = 0; k < TK; k++) {
            float4 a  = *(const float4*)&As[k][ty * 4];
            float4 bb = *(const float4*)&Bs[k][tx * 4];
            acc[0][0] += a.x * bb.x; acc[0][1] += a.x * bb.y; acc[0][2] += a.x * bb.z; acc[0][3] += a.x * bb.w;
            acc[1][0] += a.y * bb.x; acc[1][1] += a.y * bb.y; acc[1][2] += a.y * bb.z; acc[1][3] += a.y * bb.w;
            acc[2][0] += a.z * bb.x; acc[2][1] += a.z * bb.y; acc[2][2] += a.z * bb.z; acc[2][3] += a.z * bb.w;
            acc[3][0] += a.w * bb.x; acc[3][1] += a.w * bb.y; acc[3][2] += a.w * bb.z; acc[3][3] += a.w * bb.w;
        }
        __syncthreads();
    }

    float* Sb = S + (size_t)b * N * N;
#pragma unroll
    for (int i = 0; i < 4; i++) {
        const int rowi = row0A + ty * 4 + i;
        float4 o;
        o.x = acc[i][0]; o.y = acc[i][1]; o.z = acc[i][2]; o.w = acc[i][3];
        *(float4*)(Sb + (size_t)rowi * N + row0B + tx * 4) = o;
    }
    if (ti != tj) {
#pragma unroll
        for (int j = 0; j < 4; j++) {
            const int rowj = row0B + tx * 4 + j;
#pragma unroll
            for (int i = 0; i < 4; i++) {
                Sb[(size_t)rowj * N + row0A + ty * 4 + i] = acc[i][j];
            }
        }
    }
}

// ---------------------------------------------------------------------------
// Kernel 2: per row, find 32nd-largest value (exact, tie-correct) + degree.
// One wave (64 lanes) per row; 8 values per lane.
// ---------------------------------------------------------------------------
__global__ __launch_bounds__(64) void topk_thresh(const float* __restrict__ S,
                                                  float* __restrict__ thr,
                                                  float* __restrict__ dinv) {
    const int row  = blockIdx.x;        // 0..B*N-1
    const int lane = threadIdx.x;       // 0..63
    const float* Srow = S + (size_t)row * N;

    float v[8], v0[8];
#pragma unroll
    for (int k = 0; k < 8; k++) { v[k] = Srow[lane + 64 * k]; v0[k] = v[k]; }

    float lmax = -INFINITY;
#pragma unroll
    for (int k = 0; k < 8; k++) lmax = fmaxf(lmax, v[k]);

    float m = -INFINITY;
    for (int it = 0; it < K_NEIGH; it++) {
        m = lmax;
#pragma unroll
        for (int off = 32; off > 0; off >>= 1) m = fmaxf(m, __shfl_xor(m, off));
        unsigned long long ball = __ballot(lmax == m);
        int first = __ffsll(ball) - 1;
        if (lane == first) {
            bool removed = false;
#pragma unroll
            for (int k = 0; k < 8; k++) {
                if (!removed && v[k] == m) { v[k] = -INFINITY; removed = true; }
            }
            lmax = -INFINITY;
#pragma unroll
            for (int k = 0; k < 8; k++) lmax = fmaxf(lmax, v[k]);
        }
    }
    // m is the 32nd largest. Degree = count(orig >= m) (tie-inclusive, matches ref).
    int cnt = 0;
#pragma unroll
    for (int k = 0; k < 8; k++) cnt += (v0[k] >= m) ? 1 : 0;
#pragma unroll
    for (int off = 32; off > 0; off >>= 1) cnt += __shfl_xor(cnt, off);

    if (lane == 0) {
        thr[row]  = m;
        dinv[row] = rsqrtf((float)cnt);
    }
}

// ---------------------------------------------------------------------------
// Kernel 3: out[b,i,j] = (S >= thr[b,i]) ? dinv[b,i]*dinv[b,j] : 0  (in place)
// ---------------------------------------------------------------------------
__global__ __launch_bounds__(256) void scale_adj(float* __restrict__ S,
                                                 const float* __restrict__ thr,
                                                 const float* __restrict__ dinv) {
    const int idx = blockIdx.x * 256 + threadIdx.x;   // float4 index
    const int j4 = idx & 127;            // N/4 = 128
    const int i  = (idx >> 7) & (N - 1);
    const int b  = idx >> 16;            // 128*512 = 65536
    const int row = (b << 9) | i;

    const float t  = thr[row];
    const float di = dinv[row];
    float4 s  = ((const float4*)S)[idx];
    float4 dj = ((const float4*)dinv)[(b << 7) | j4];

    float4 o;
    o.x = (s.x >= t) ? di * dj.x : 0.f;
    o.y = (s.y >= t) ? di * dj.y : 0.f;
    o.z = (s.z >= t) ? di * dj.z : 0.f;
    o.w = (s.w >= t) ? di * dj.w : 0.f;
    ((float4*)S)[idx] = o;
}

// ---------------------------------------------------------------------------
extern "C" void kernel_launch(void* const* d_in, const int* in_sizes, int n_in,
                              void* d_out, int out_size, void* d_ws, size_t ws_size,
                              hipStream_t stream) {
    const float* x = (const float*)d_in[0];
    float* out = (float*)d_out;            // stages S, then overwritten in place
    float* thr  = (float*)d_ws;            // B*N floats
    float* dinv = thr + B * N;             // B*N floats  (total 256 KB of ws)

    dim3 g1(B, 36);                        // 36 = upper-tri tile pairs of 8x8
    gemm_syrk<<<g1, 256, 0, stream>>>(x, out);
    topk_thresh<<<B * N, 64, 0, stream>>>(out, thr, dinv);
    const int total4 = B * N * N / 4;      // 4,194,304
    scale_adj<<<total4 / 256, 256, 0, stream>>>(out, thr, dinv);
}